// Round 1
// baseline (541.547 us; speedup 1.0000x reference)
//
#include <hip/hip_runtime.h>
#include <hip/hip_bf16.h>

#define Bsz  4096
#define Tn   256
#define CIN  16
#define HID  64
#define NCLS 10
#define MB   8          // batch rows per block (M of MFMA tile padded to 16)

typedef __attribute__((ext_vector_type(8))) short short8;
typedef __attribute__((ext_vector_type(4))) float f32x4;

__device__ inline ushort f2bf(float f) {
    union { float f; unsigned u; } x; x.f = f;
    unsigned r = (x.u + 0x7FFF + ((x.u >> 16) & 1)) >> 16;  // RNE
    return (ushort)r;
}
__device__ inline float sigmoidf_(float v) { return 1.f / (1.f + __expf(-v)); }
__device__ inline float tanhf_(float v)    { return 1.f - 2.f / (1.f + __expf(2.f * v)); }

__global__ __launch_bounds__(256, 2) void dualrnn_kernel(
    const float* __restrict__ x,  const float* __restrict__ Wl, const float* __restrict__ bl,
    const float* __restrict__ Wc, const float* __restrict__ bc,
    const float* __restrict__ Wd, const float* __restrict__ bd,
    float* __restrict__ out)
{
    __shared__ alignas(16) ushort comb[16][104];   // [batch_row][k], k: 0..15 x, 16..79 h, 80..95 zero-pad
    const int tid  = threadIdx.x;
    const int wave = tid >> 6;
    const int lane = tid & 63;
    const int col  = lane & 15;   // MFMA 16-dim index (n or m)
    const int grp  = lane >> 4;   // k-chunk / row-group
    const int b0   = blockIdx.x * MB;

    for (int i = tid; i < 16 * 104; i += 256) ((ushort*)comb)[i] = 0;

    // ---- preload W_lstm fragments (loop-invariant, stay in VGPRs) ----
    // wave w owns units u = 16w + col; gate tiles: rows g*64 + u of W_lstm
    short8 wf[4][3];
    float  bias[4];
#pragma unroll
    for (int g = 0; g < 4; ++g) {
        const int R = g * 64 + wave * 16 + col;
        bias[g] = bl[R];
#pragma unroll
        for (int kt = 0; kt < 3; ++kt) {
#pragma unroll
            for (int i = 0; i < 8; ++i) {
                const int k = kt * 32 + grp * 8 + i;
                const float v = (k < 80) ? Wl[R * 80 + k] : 0.f;
                wf[g][kt][i] = (short)f2bf(v);
            }
        }
    }
    // class+dec head: B[k][n], n<10 -> W_class[n][k], n==10 -> W_dec[k], else 0
    short8 wcd[2];
#pragma unroll
    for (int kt = 0; kt < 2; ++kt)
#pragma unroll
        for (int i = 0; i < 8; ++i) {
            const int k = kt * 32 + grp * 8 + i;
            float v = 0.f;
            if (col < 10)       v = Wc[col * 64 + k];
            else if (col == 10) v = Wd[k];
            wcd[kt][i] = (short)f2bf(v);
        }
    const float bcd = (col < 10) ? bc[col] : ((col == 10) ? bd[0] : 0.f);

    float cst[4] = {0.f, 0.f, 0.f, 0.f};   // c state, accumulator layout rows grp*4+j, unit 16*wave+col
    float pnd = 1.f;                        // tracked by lanes (grp<2, col==10), row = grp*4 + wave

    // prologue: x_0 into comb (h part already zero)
    if (tid < 128) {
        const int r = tid >> 4, ch = tid & 15;
        comb[r][ch] = f2bf(x[((size_t)(b0 + r) * Tn + 0) * CIN + ch]);
    }
    __syncthreads();

    float* lp_out = out;                               // [B][T][10]
    float* pt_out = out + (size_t)Bsz * Tn * NCLS;     // [B][T]

    for (int t = 0; t < Tn; ++t) {
        // prefetch x_{t+1} into regs (written to LDS after barrier)
        float xv = 0.f;
        const int xr = tid >> 4, xc = tid & 15;
        if (t + 1 < Tn && tid < 128)
            xv = x[((size_t)(b0 + xr) * Tn + (t + 1)) * CIN + xc];

        // A fragments: row = col (batch), k = kt*32 + grp*8 .. +7
        short8 a0 = *(const short8*)&comb[col][ 0 + grp * 8];
        short8 a1 = *(const short8*)&comb[col][32 + grp * 8];
        short8 a2 = *(const short8*)&comb[col][64 + grp * 8];

        f32x4 acc[4];
#pragma unroll
        for (int g = 0; g < 4; ++g) {
            f32x4 z = {0.f, 0.f, 0.f, 0.f};
            z = __builtin_amdgcn_mfma_f32_16x16x32_bf16(a0, wf[g][0], z, 0, 0, 0);
            z = __builtin_amdgcn_mfma_f32_16x16x32_bf16(a1, wf[g][1], z, 0, 0, 0);
            z = __builtin_amdgcn_mfma_f32_16x16x32_bf16(a2, wf[g][2], z, 0, 0, 0);
            acc[g] = z;
        }

        float hv[4];
#pragma unroll
        for (int j = 0; j < 4; ++j) {
            const float gi = sigmoidf_(acc[0][j] + bias[0]);
            const float gf = sigmoidf_(acc[1][j] + bias[1]);
            const float go = sigmoidf_(acc[2][j] + bias[2]);
            const float gg = tanhf_  (acc[3][j] + bias[3]);
            const float cn = gf * cst[j] + gi * gg;
            cst[j] = cn;
            hv[j]  = go * tanhf_(cn);
        }

        __syncthreads();   // everyone finished reading comb{x_t, h_{t-1}}

        const int hc = 16 + wave * 16 + col;
#pragma unroll
        for (int j = 0; j < 4; ++j)
            comb[grp * 4 + j][hc] = f2bf(hv[j]);
        if (t + 1 < Tn && tid < 128)
            comb[xr][xc] = f2bf(xv);

        __syncthreads();   // comb now {x_{t+1}, h_t}

        // class/dec head on h_t (cols 16..79), K=64 -> 2 k-tiles; redundant per wave
        short8 ha0 = *(const short8*)&comb[col][16 +  0 + grp * 8];
        short8 ha1 = *(const short8*)&comb[col][16 + 32 + grp * 8];
        f32x4 cz = {0.f, 0.f, 0.f, 0.f};
        cz = __builtin_amdgcn_mfma_f32_16x16x32_bf16(ha0, wcd[0], cz, 0, 0, 0);
        cz = __builtin_amdgcn_mfma_f32_16x16x32_bf16(ha1, wcd[1], cz, 0, 0, 0);

        // wave w handles accumulator slot j == w (row = grp*4 + w)
        float v = (wave & 1) ? ((wave & 2) ? cz[3] : cz[1])
                             : ((wave & 2) ? cz[2] : cz[0]);
        v += bcd;

        float mx = (col < 10) ? v : -3.4e38f;
#pragma unroll
        for (int m_ = 1; m_ < 16; m_ <<= 1)
            mx = fmaxf(mx, __shfl_xor(mx, m_, 16));
        float e = (col < 10) ? __expf(v - mx) : 0.f;
        float s = e;
#pragma unroll
        for (int m_ = 1; m_ < 16; m_ <<= 1)
            s += __shfl_xor(s, m_, 16);
        const float lse = __logf(s);

        const int row = grp * 4 + wave;
        if (grp < 2) {                                  // rows 0..7 are real (MB=8)
            const size_t bt = (size_t)(b0 + row) * Tn + t;
            if (col < 10) {
                lp_out[bt * NCLS + col] = v - mx - lse;
            } else if (col == 10) {
                const float d = sigmoidf_(v);
                pt_out[bt] = (t == Tn - 1) ? pnd : d * pnd;
                pnd *= (1.f - d);
            }
        }
    }
}

extern "C" void kernel_launch(void* const* d_in, const int* in_sizes, int n_in,
                              void* d_out, int out_size, void* d_ws, size_t ws_size,
                              hipStream_t stream) {
    const float* x  = (const float*)d_in[0];
    const float* Wl = (const float*)d_in[1];
    const float* bl = (const float*)d_in[2];
    const float* Wc = (const float*)d_in[3];
    const float* bc = (const float*)d_in[4];
    const float* Wd = (const float*)d_in[5];
    const float* bd = (const float*)d_in[6];
    float* out = (float*)d_out;

    dim3 grid(Bsz / MB), block(256);
    hipLaunchKernelGGL(dualrnn_kernel, grid, block, 0, stream,
                       x, Wl, bl, Wc, bc, Wd, bd, out);
}

// Round 2
// 159.743 us; speedup vs baseline: 3.3901x; 3.3901x over previous
//
#include <hip/hip_runtime.h>
#include <hip/hip_bf16.h>

#define Bsz  4096
#define Tn   256
#define CIN  16
#define NCLS 10
#define MB   16          // full 16-row MFMA tile per block

typedef __attribute__((ext_vector_type(8))) short short8;
typedef __attribute__((ext_vector_type(4))) float f32x4;

#if __has_builtin(__builtin_amdgcn_exp2f)
#define EXP2F(x) __builtin_amdgcn_exp2f(x)
#else
#define EXP2F(x) exp2f(x)
#endif
#define RCPF(x) __builtin_amdgcn_rcpf(x)

__device__ inline ushort f2bf(float f) {
    union { float f; unsigned u; } x; x.f = f;
    return (ushort)((x.u + 0x7FFF + ((x.u >> 16) & 1)) >> 16);  // RNE
}

__global__ __launch_bounds__(512, 2) void dualrnn_kernel(
    const float* __restrict__ x,  const float* __restrict__ Wl, const float* __restrict__ bl,
    const float* __restrict__ Wc, const float* __restrict__ bc,
    const float* __restrict__ Wd, const float* __restrict__ bd,
    float* __restrict__ out)
{
    // double-buffered: [parity][batch_row][k]; k: 0..15 x, 16..79 h, 80..95 pad(0)
    __shared__ alignas(16) ushort comb[2][16][104];
    const int tid  = threadIdx.x;
    const int wave = tid >> 6;
    const int lane = tid & 63;
    const int col  = lane & 15;
    const int grp  = lane >> 4;
    const int b0   = blockIdx.x * MB;
    const bool gatew = (wave < 4);   // waves 0-3: LSTM gates; waves 4-7: head

    for (int i = tid; i < 2 * 16 * 104; i += 512) ((ushort*)comb)[i] = 0;

    // ---- preload weights (role-specific, loop-invariant in VGPRs) ----
    short8 wf[4][3]; float bias[4] = {0, 0, 0, 0};
    short8 wcd[2];   float bcd = 0.f;
    if (gatew) {
        // fold exp2 scale: sigmoid gates i,f,o get -log2(e); tanh gate g gets +2*log2(e)
#pragma unroll
        for (int g = 0; g < 4; ++g) {
            const float sc = (g == 3) ? 2.885390082f : -1.442695041f;
            const int R = g * 64 + wave * 16 + col;
            bias[g] = bl[R] * sc;
#pragma unroll
            for (int kt = 0; kt < 3; ++kt)
#pragma unroll
                for (int i = 0; i < 8; ++i) {
                    const int k = kt * 32 + grp * 8 + i;
                    wf[g][kt][i] = (short)f2bf(k < 80 ? Wl[R * 80 + k] * sc : 0.f);
                }
        }
    } else {
#pragma unroll
        for (int kt = 0; kt < 2; ++kt)
#pragma unroll
            for (int i = 0; i < 8; ++i) {
                const int k = kt * 32 + grp * 8 + i;
                float v = 0.f;
                if (col < 10)       v = Wc[col * 64 + k];
                else if (col == 10) v = Wd[k];
                wcd[kt][i] = (short)f2bf(v);
            }
        bcd = (col < 10) ? bc[col] : ((col == 10) ? bd[0] : 0.f);
    }

    __syncthreads();   // zeroing done before x_0 write (avoid zero/x race)

    if (tid < 256) {   // x_0 into comb[0]; h-section stays zero
        const int r = tid >> 4, ch = tid & 15;
        comb[0][r][ch] = f2bf(x[((size_t)(b0 + r) * Tn) * CIN + ch]);
    }
    __syncthreads();

    float cst[4] = {0, 0, 0, 0};   // c state (gate waves), rows grp*4+j, unit 16*wave+col
    float pnd = 1.f;               // head waves, lanes col==10, row grp*4+hw

    const int hw  = wave & 3;            // head-wave id 0..3
    const int row = grp * 4 + hw;        // output row this head thread owns (slot j==hw)
    float* lp_p = out + ((size_t)(b0 + row) * Tn) * NCLS + col;              // [B][T][10]
    float* pt_p = out + (size_t)Bsz * Tn * NCLS + (size_t)(b0 + row) * Tn;   // [B][T]
    const int t2 = hw * 64 + lane;       // 0..255 across head waves
    const int xr = t2 >> 4, xc = t2 & 15;
    const float* xp = x + ((size_t)(b0 + xr) * Tn + 1) * CIN + xc;           // x_{t+1}

    // iter t: read comb[t&1] = {x_t, h_{t-1}}; gates write h_t, head writes x_{t+1}
    // into comb[(t+1)&1]; head outputs step t-1 from h_{t-1}. One barrier/iter.
    for (int t = 0; t < Tn; ++t) {
        const ushort (*rdb)[104] = comb[t & 1];
        ushort (*wrb)[104] = comb[(t + 1) & 1];
        if (gatew) {
            const short8 a0 = *(const short8*)&rdb[col][ 0 + grp * 8];
            const short8 a1 = *(const short8*)&rdb[col][32 + grp * 8];
            const short8 a2 = *(const short8*)&rdb[col][64 + grp * 8];
            f32x4 acc[4];
#pragma unroll
            for (int g = 0; g < 4; ++g) {
                f32x4 z = {0, 0, 0, 0};
                z = __builtin_amdgcn_mfma_f32_16x16x32_bf16(a0, wf[g][0], z, 0, 0, 0);
                z = __builtin_amdgcn_mfma_f32_16x16x32_bf16(a1, wf[g][1], z, 0, 0, 0);
                z = __builtin_amdgcn_mfma_f32_16x16x32_bf16(a2, wf[g][2], z, 0, 0, 0);
                acc[g] = z;
            }
            const int hc = 16 + wave * 16 + col;
#pragma unroll
            for (int j = 0; j < 4; ++j) {
                const float gi = RCPF(1.f + EXP2F(acc[0][j] + bias[0]));
                const float gf = RCPF(1.f + EXP2F(acc[1][j] + bias[1]));
                const float go = RCPF(1.f + EXP2F(acc[2][j] + bias[2]));
                const float gg = 1.f - 2.f * RCPF(1.f + EXP2F(acc[3][j] + bias[3]));
                const float cn = gf * cst[j] + gi * gg;
                cst[j] = cn;
                const float th = 1.f - 2.f * RCPF(1.f + EXP2F(2.885390082f * cn));
                wrb[grp * 4 + j][hc] = f2bf(go * th);
            }
        } else {
            const short8 ha0 = *(const short8*)&rdb[col][16 + grp * 8];
            const short8 ha1 = *(const short8*)&rdb[col][48 + grp * 8];
            float xv = 0.f;
            const bool ldx = (t + 1 < Tn);
            if (ldx) xv = *xp;
            xp += CIN;
            f32x4 cz = {0, 0, 0, 0};
            cz = __builtin_amdgcn_mfma_f32_16x16x32_bf16(ha0, wcd[0], cz, 0, 0, 0);
            cz = __builtin_amdgcn_mfma_f32_16x16x32_bf16(ha1, wcd[1], cz, 0, 0, 0);
            if (ldx) wrb[xr][xc] = f2bf(xv);
            if (t > 0) {
                float v = (hw & 1) ? ((hw & 2) ? cz[3] : cz[1])
                                   : ((hw & 2) ? cz[2] : cz[0]);
                v += bcd;
                // |logits| small -> skip max-subtraction; sum exp over 16-lane group
                float s = (col < 10) ? __expf(v) : 0.f;
                s += __int_as_float(__builtin_amdgcn_ds_swizzle(__float_as_int(s), 0x041F));
                s += __int_as_float(__builtin_amdgcn_ds_swizzle(__float_as_int(s), 0x081F));
                s += __int_as_float(__builtin_amdgcn_ds_swizzle(__float_as_int(s), 0x101F));
                s += __int_as_float(__builtin_amdgcn_ds_swizzle(__float_as_int(s), 0x201F));
                const float lse = __logf(s);
                if (col < 10) {
                    lp_p[0] = v - lse;
                } else if (col == 10) {
                    const float d = RCPF(1.f + __expf(-v));
                    pt_p[0] = d * pnd;
                    pnd *= (1.f - d);
                }
                lp_p += NCLS;
                pt_p += 1;
            }
        }
        __syncthreads();
    }

    // epilogue: output step Tn-1 from h_{Tn-1} in comb[Tn&1]
    if (!gatew) {
        const ushort (*rdb)[104] = comb[Tn & 1];
        const short8 ha0 = *(const short8*)&rdb[col][16 + grp * 8];
        const short8 ha1 = *(const short8*)&rdb[col][48 + grp * 8];
        f32x4 cz = {0, 0, 0, 0};
        cz = __builtin_amdgcn_mfma_f32_16x16x32_bf16(ha0, wcd[0], cz, 0, 0, 0);
        cz = __builtin_amdgcn_mfma_f32_16x16x32_bf16(ha1, wcd[1], cz, 0, 0, 0);
        float v = (hw & 1) ? ((hw & 2) ? cz[3] : cz[1])
                           : ((hw & 2) ? cz[2] : cz[0]);
        v += bcd;
        float s = (col < 10) ? __expf(v) : 0.f;
        s += __int_as_float(__builtin_amdgcn_ds_swizzle(__float_as_int(s), 0x041F));
        s += __int_as_float(__builtin_amdgcn_ds_swizzle(__float_as_int(s), 0x081F));
        s += __int_as_float(__builtin_amdgcn_ds_swizzle(__float_as_int(s), 0x101F));
        s += __int_as_float(__builtin_amdgcn_ds_swizzle(__float_as_int(s), 0x201F));
        const float lse = __logf(s);
        if (col < 10)       lp_p[0] = v - lse;
        else if (col == 10) pt_p[0] = pnd;   // is_last: Pt = pnd_{T-1}
    }
}

extern "C" void kernel_launch(void* const* d_in, const int* in_sizes, int n_in,
                              void* d_out, int out_size, void* d_ws, size_t ws_size,
                              hipStream_t stream) {
    const float* x  = (const float*)d_in[0];
    const float* Wl = (const float*)d_in[1];
    const float* bl = (const float*)d_in[2];
    const float* Wc = (const float*)d_in[3];
    const float* bc = (const float*)d_in[4];
    const float* Wd = (const float*)d_in[5];
    const float* bd = (const float*)d_in[6];
    float* out = (float*)d_out;

    dim3 grid(Bsz / MB), block(512);
    hipLaunchKernelGGL(dualrnn_kernel, grid, block, 0, stream,
                       x, Wl, bl, Wc, bc, Wd, bd, out);
}

// Round 3
// 150.203 us; speedup vs baseline: 3.6054x; 1.0635x over previous
//
#include <hip/hip_runtime.h>
#include <hip/hip_bf16.h>

#define Bsz  4096
#define Tn   256
#define CIN  16
#define NCLS 10
#define MB   16          // full 16-row MFMA tile per block

typedef __attribute__((ext_vector_type(8))) short short8;
typedef __attribute__((ext_vector_type(4))) float f32x4;

#if __has_builtin(__builtin_amdgcn_exp2f)
#define EXP2F(x) __builtin_amdgcn_exp2f(x)
#else
#define EXP2F(x) exp2f(x)
#endif
#define RCPF(x) __builtin_amdgcn_rcpf(x)

#define LOG2E 1.442695041f

__device__ inline ushort f2bf(float f) {
    union { float f; unsigned u; } x; x.f = f;
    return (ushort)((x.u + 0x7FFF + ((x.u >> 16) & 1)) >> 16);  // RNE
}

__global__ __launch_bounds__(512, 2) void dualrnn_kernel(
    const float* __restrict__ x,  const float* __restrict__ Wl, const float* __restrict__ bl,
    const float* __restrict__ Wc, const float* __restrict__ bc,
    const float* __restrict__ Wd, const float* __restrict__ bd,
    float* __restrict__ out)
{
    // double-buffered: [parity][batch_row][k]; k: 0..15 x, 16..79 h, 80..95 pad(0)
    __shared__ alignas(16) ushort comb[2][16][104];
    const int tid  = threadIdx.x;
    const int wave = tid >> 6;
    const int lane = tid & 63;
    const int col  = lane & 15;
    const int grp  = lane >> 4;
    const int b0   = blockIdx.x * MB;
    const bool gatew = (wave < 4);   // waves 0-3: LSTM gates; waves 4-7: head

    for (int i = tid; i < 2 * 16 * 104; i += 512) ((ushort*)comb)[i] = 0;

    // ---- preload weights (role-specific, loop-invariant in VGPRs) ----
    // gates: fold exp2 scale; sigmoid gates i,f,o: -log2(e); tanh gate g: +2*log2(e).
    // bias folded into the MFMA C-operand (biasv).
    short8 wf[4][3]; f32x4 biasv[4];
    short8 wcd[2];   f32x4 bcdv;
    if (gatew) {
#pragma unroll
        for (int g = 0; g < 4; ++g) {
            const float sc = (g == 3) ? 2.f * LOG2E : -LOG2E;
            const int R = g * 64 + wave * 16 + col;
            const float bv = bl[R] * sc;
            biasv[g] = (f32x4){bv, bv, bv, bv};
#pragma unroll
            for (int kt = 0; kt < 3; ++kt)
#pragma unroll
                for (int i = 0; i < 8; ++i) {
                    const int k = kt * 32 + grp * 8 + i;
                    wf[g][kt][i] = (short)f2bf(k < 80 ? Wl[R * 80 + k] * sc : 0.f);
                }
        }
    } else {
        // class lanes (col<10): natural scale. dec lane (col==10): fold -log2(e).
#pragma unroll
        for (int kt = 0; kt < 2; ++kt)
#pragma unroll
            for (int i = 0; i < 8; ++i) {
                const int k = kt * 32 + grp * 8 + i;
                float v = 0.f;
                if (col < 10)       v = Wc[col * 64 + k];
                else if (col == 10) v = Wd[k] * -LOG2E;
                wcd[kt][i] = (short)f2bf(v);
            }
        const float bv = (col < 10) ? bc[col] : ((col == 10) ? bd[0] * -LOG2E : 0.f);
        bcdv = (f32x4){bv, bv, bv, bv};
    }

    __syncthreads();   // zeroing done before x_0 write (avoid zero/x race)

    if (tid < 256) {   // x_0 into comb[0]; h-section stays zero
        const int r = tid >> 4, ch = tid & 15;
        comb[0][r][ch] = f2bf(x[((size_t)(b0 + r) * Tn) * CIN + ch]);
    }
    __syncthreads();

    float cst[4] = {0, 0, 0, 0};   // c state (gate waves), rows grp*4+j, unit 16*wave+col
    float pnd = 1.f;               // head waves, lanes col==10, row grp*4+hw

    const int hw  = wave & 3;            // head-wave id 0..3
    const int row = grp * 4 + hw;        // output row this head thread owns (slot j==hw)
    float* lp_p = out + ((size_t)(b0 + row) * Tn) * NCLS + col;              // [B][T][10]
    float* pt_p = out + (size_t)Bsz * Tn * NCLS + (size_t)(b0 + row) * Tn;   // [B][T]
    const int t2 = hw * 64 + lane;       // 0..255 across head waves
    const int xr = t2 >> 4, xc = t2 & 15;
    // 2-deep x prefetch: xva holds x_{t+1} (written this iter); load x_{t+2} now.
    float xva = 0.f;
    const float* xp = x + ((size_t)(b0 + xr) * Tn + 2) * CIN + xc;
    if (!gatew) xva = x[((size_t)(b0 + xr) * Tn + 1) * CIN + xc];

    // iter t: read comb[t&1] = {x_t, h_{t-1}}; gates write h_t, head writes x_{t+1}
    // into comb[(t+1)&1]; head outputs step t-1 from h_{t-1}. One barrier/iter.
    for (int t = 0; t < Tn; ++t) {
        const ushort (*rdb)[104] = comb[t & 1];
        ushort (*wrb)[104] = comb[(t + 1) & 1];
        if (gatew) {
            const short8 a0 = *(const short8*)&rdb[col][ 0 + grp * 8];
            const short8 a1 = *(const short8*)&rdb[col][32 + grp * 8];
            const short8 a2 = *(const short8*)&rdb[col][64 + grp * 8];
            f32x4 acc[4];
#pragma unroll
            for (int g = 0; g < 4; ++g) {
                f32x4 z = biasv[g];
                z = __builtin_amdgcn_mfma_f32_16x16x32_bf16(a0, wf[g][0], z, 0, 0, 0);
                z = __builtin_amdgcn_mfma_f32_16x16x32_bf16(a1, wf[g][1], z, 0, 0, 0);
                z = __builtin_amdgcn_mfma_f32_16x16x32_bf16(a2, wf[g][2], z, 0, 0, 0);
                acc[g] = z;
            }
            const int hc = 16 + wave * 16 + col;
#pragma unroll
            for (int j = 0; j < 4; ++j) {
                // gi=1/A, gf=1/B, tanh_g=G2/G1, go=1/O
                const float ei = EXP2F(acc[0][j]);
                const float ef = EXP2F(acc[1][j]);
                const float eo = EXP2F(acc[2][j]);
                const float eg = EXP2F(acc[3][j]);
                const float A  = 1.f + ei, Bv = 1.f + ef;
                const float G1 = eg + 1.f, G2 = eg - 1.f, O = 1.f + eo;
                const float t0  = A * G1;
                const float num = cst[j] * t0 + G2 * Bv;
                const float den = Bv * t0;
                const float cn  = num * RCPF(den);
                cst[j] = cn;
                const float e2 = EXP2F(2.f * LOG2E * cn);
                const float h  = (e2 - 1.f) * RCPF((e2 + 1.f) * O);
                wrb[grp * 4 + j][hc] = f2bf(h);
            }
        } else {
            // issue x_{t+2} load first (covered by this whole step)
            float xvn = 0.f;
            if (t + 2 < Tn) xvn = *xp;
            xp += CIN;
            const short8 ha0 = *(const short8*)&rdb[col][16 + grp * 8];
            const short8 ha1 = *(const short8*)&rdb[col][48 + grp * 8];
            f32x4 cz = bcdv;
            cz = __builtin_amdgcn_mfma_f32_16x16x32_bf16(ha0, wcd[0], cz, 0, 0, 0);
            cz = __builtin_amdgcn_mfma_f32_16x16x32_bf16(ha1, wcd[1], cz, 0, 0, 0);
            if (t + 1 < Tn) wrb[xr][xc] = f2bf(xva);   // x_{t+1}, loaded LAST iter
            xva = xvn;
            if (t > 0) {
                float v = (hw & 1) ? ((hw & 2) ? cz[3] : cz[1])
                                   : ((hw & 2) ? cz[2] : cz[0]);
                // |logits| small -> skip max-subtraction; sum exp over 16-lane group
                float s = (col < 10) ? EXP2F(v * LOG2E) : 0.f;
                s += __int_as_float(__builtin_amdgcn_ds_swizzle(__float_as_int(s), 0x041F));
                s += __int_as_float(__builtin_amdgcn_ds_swizzle(__float_as_int(s), 0x081F));
                s += __int_as_float(__builtin_amdgcn_ds_swizzle(__float_as_int(s), 0x101F));
                s += __int_as_float(__builtin_amdgcn_ds_swizzle(__float_as_int(s), 0x201F));
                const float lse = __logf(s);
                if (col < 10) {
                    lp_p[0] = v - lse;
                } else if (col == 10) {
                    const float d = RCPF(1.f + EXP2F(v));   // -log2e folded in wcd
                    pt_p[0] = d * pnd;
                    pnd *= (1.f - d);
                }
                lp_p += NCLS;
                pt_p += 1;
            }
        }
        __syncthreads();
    }

    // epilogue: output step Tn-1 from h_{Tn-1} in comb[Tn&1]
    if (!gatew) {
        const ushort (*rdb)[104] = comb[Tn & 1];
        const short8 ha0 = *(const short8*)&rdb[col][16 + grp * 8];
        const short8 ha1 = *(const short8*)&rdb[col][48 + grp * 8];
        f32x4 cz = bcdv;
        cz = __builtin_amdgcn_mfma_f32_16x16x32_bf16(ha0, wcd[0], cz, 0, 0, 0);
        cz = __builtin_amdgcn_mfma_f32_16x16x32_bf16(ha1, wcd[1], cz, 0, 0, 0);
        float v = (hw & 1) ? ((hw & 2) ? cz[3] : cz[1])
                           : ((hw & 2) ? cz[2] : cz[0]);
        float s = (col < 10) ? EXP2F(v * LOG2E) : 0.f;
        s += __int_as_float(__builtin_amdgcn_ds_swizzle(__float_as_int(s), 0x041F));
        s += __int_as_float(__builtin_amdgcn_ds_swizzle(__float_as_int(s), 0x081F));
        s += __int_as_float(__builtin_amdgcn_ds_swizzle(__float_as_int(s), 0x101F));
        s += __int_as_float(__builtin_amdgcn_ds_swizzle(__float_as_int(s), 0x201F));
        const float lse = __logf(s);
        if (col < 10)       lp_p[0] = v - lse;
        else if (col == 10) pt_p[0] = pnd;   // is_last: Pt = pnd_{T-1}
    }
}

extern "C" void kernel_launch(void* const* d_in, const int* in_sizes, int n_in,
                              void* d_out, int out_size, void* d_ws, size_t ws_size,
                              hipStream_t stream) {
    const float* x  = (const float*)d_in[0];
    const float* Wl = (const float*)d_in[1];
    const float* bl = (const float*)d_in[2];
    const float* Wc = (const float*)d_in[3];
    const float* bc = (const float*)d_in[4];
    const float* Wd = (const float*)d_in[5];
    const float* bd = (const float*)d_in[6];
    float* out = (float*)d_out;

    dim3 grid(Bsz / MB), block(512);
    hipLaunchKernelGGL(dualrnn_kernel, grid, block, 0, stream,
                       x, Wl, bl, Wc, bc, Wd, bd, out);
}